// Round 2
// baseline (1049.737 us; speedup 1.0000x reference)
//
#include <hip/hip_runtime.h>
#include <stdint.h>

// Problem constants (from reference): B=2, NH=8, N=4096, D=64, K2=49
#define NB   2
#define NHD  8
#define NN   4096
#define ND   64
#define K2   49
#define RK   (ND * K2)   // 3136 floats per (b,h,n) row of v_local

typedef const __attribute__((address_space(1))) void* gas_t;
typedef __attribute__((address_space(3))) void* las_t;

// Async global->LDS copy. LDS dest is wave-uniform base; lane l writes base + l*size.
__device__ __forceinline__ void cp16(const void* g, void* l) {
  __builtin_amdgcn_global_load_lds((gas_t)g, (las_t)l, 16, 0, 0);
}
__device__ __forceinline__ void cp4(const void* g, void* l) {
  __builtin_amdgcn_global_load_lds((gas_t)g, (las_t)l, 4, 0, 0);
}

// One wave per (b,h,n) row; 4 waves (4 rows) per block; fully wave-private
// (no __syncthreads -> no cross-wave coupling, staging loads stay in flight).
__global__ __launch_bounds__(256, 3) void swattn_av_kernel(
    const float* __restrict__ q,        // [B,NH,N,D]
    const float* __restrict__ att_loc,  // [B,NH,N,K2]
    const float* __restrict__ v,        // [B,NH,N,D,K2]
    const float* __restrict__ tok,      // [NH,D,K2]
    const float* __restrict__ bias,     // [NH,N,K2]
    float* __restrict__ out)            // [B,NH,N,D]
{
  __shared__ __align__(16) float v_lds[4][RK];   // 50176 B
  __shared__ __align__(16) float q_lds[4][ND];   //  1024 B
  __shared__ __align__(16) float a_lds[4][64];   //  1024 B (attn padded to 64)

  const int wave = threadIdx.x >> 6;
  const int lane = threadIdx.x & 63;
  const size_t row = ((size_t)blockIdx.x << 2) | (size_t)wave;  // [0, 65536)
  const int n    = (int)(row & (NN - 1));
  const int h    = (int)((row >> 12) & (NHD - 1));   // NN = 2^12
  const int kk   = lane < K2 ? lane : K2 - 1;        // clamp: lanes 49..63 dup k=48

  // ---- phase-1 global loads FIRST (so later waitcnts don't drain the v-stage) ----
  const float qv = q[row * ND + (size_t)lane];
  const float* Th = tok + (size_t)h * RK + kk;       // T[h][d][kk], stride K2 over d
  float tv[ND];
#pragma unroll
  for (int d = 0; d < ND; ++d) tv[d] = Th[d * K2];   // L1/L2-resident (12.5 KB per h)
  const float bl = bias[((size_t)h * NN + n) * K2 + kk] + att_loc[row * K2 + kk];

  // ---- async stage this row's v (3136 floats = 12544 B) into LDS, coalesced ----
  const float* vrow = v + row * RK;
  float* lb = &v_lds[wave][0];
#pragma unroll
  for (int i = 0; i < 12; ++i)
    cp16(vrow + i * 256 + lane * 4, lb + i * 256);   // 64 lanes x 16 B = 1024 B each
  cp4(vrow + 3072 + lane, lb + 3072);                // 64-float tail

  // ---- phase 1: attn[k] = q . T[:,k] + bias + local (lanes = k, via q broadcast) ----
  q_lds[wave][lane] = qv;
  asm volatile("s_waitcnt lgkmcnt(0)" ::: "memory");  // q_lds visible wave-wide
  float acc = bl;
  const float* ql = &q_lds[wave][0];
#pragma unroll
  for (int d = 0; d < ND; ++d) acc = fmaf(ql[d], tv[d], acc);
  a_lds[wave][lane] = acc;

  // ---- drain v-stage + attn write, then phase 2: out[d] = sum_k attn[k]*v[d,k] ----
  asm volatile("s_waitcnt vmcnt(0) lgkmcnt(0)" ::: "memory");
  const float* vl = &v_lds[wave][(size_t)lane * K2];  // stride 49 (odd) -> conflict-free
  const float* al = &a_lds[wave][0];                  // uniform addr -> LDS broadcast
  float o = 0.f;
#pragma unroll
  for (int k = 0; k < K2; ++k) o = fmaf(al[k], vl[k], o);
  out[row * ND + (size_t)lane] = o;
}

extern "C" void kernel_launch(void* const* d_in, const int* in_sizes, int n_in,
                              void* d_out, int out_size, void* d_ws, size_t ws_size,
                              hipStream_t stream) {
  const float* q    = (const float*)d_in[0];
  const float* aloc = (const float*)d_in[1];
  const float* v    = (const float*)d_in[2];
  const float* tok  = (const float*)d_in[3];
  const float* bias = (const float*)d_in[4];
  // d_in[5..7] = window_size, H, W (unused; geometry is baked into constants)
  float* out = (float*)d_out;

  dim3 grid((NB * NHD * NN) / 4);  // 16384 blocks, 4 rows each
  dim3 block(256);
  hipLaunchKernelGGL(swattn_av_kernel, grid, block, 0, stream,
                     q, aloc, v, tok, bias, out);
}